// Round 1
// baseline (11655.608 us; speedup 1.0000x reference)
//
#include <hip/hip_runtime.h>

#define BATCH   64
#define TSTEPS  256
#define NINPUT  512
#define HDIM    1024
#define G4      4096   // 4*HDIM
#define NWG     128    // scan workgroups
#define NHC     8      // h-columns owned per scan WG

typedef __attribute__((ext_vector_type(8))) short short8;
typedef __attribute__((ext_vector_type(4))) float f32x4;

static __device__ __forceinline__ unsigned short f2bf(float x) {
    unsigned u = __float_as_uint(x);
    unsigned r = 0x7fffu + ((u >> 16) & 1u);
    return (unsigned short)((u + r) >> 16);
}
static __device__ __forceinline__ float bf2f(unsigned short b) {
    return __uint_as_float(((unsigned)b) << 16);
}

// ---------------- float -> bf16 conversion (vectorized, grid-stride) ----------------
__global__ void k_f2b(const float* __restrict__ in, unsigned short* __restrict__ out, long n) {
    long i = (long)blockIdx.x * blockDim.x + threadIdx.x;
    long stride = (long)gridDim.x * blockDim.x;
    for (long j = i * 4; j < n; j += stride * 4) {
        float4 v = *reinterpret_cast<const float4*>(in + j);
        ushort4 o;
        o.x = f2bf(v.x); o.y = f2bf(v.y); o.z = f2bf(v.z); o.w = f2bf(v.w);
        *reinterpret_cast<ushort4*>(out + j) = o;
    }
}

// ---------------- bias combine + h0 init ----------------
__global__ void k_prep_small(const float* __restrict__ bih0, const float* __restrict__ bhh0,
                             const float* __restrict__ bih1, const float* __restrict__ bhh1,
                             float* __restrict__ bb0, float* __restrict__ bb1,
                             const float* __restrict__ h0,
                             unsigned short* __restrict__ hA0, unsigned short* __restrict__ hA1) {
    int i = blockIdx.x * blockDim.x + threadIdx.x;
    if (i < G4) { bb0[i] = bih0[i] + bhh0[i]; bb1[i] = bih1[i] + bhh1[i]; }
    if (i < BATCH * HDIM) {
        hA0[i] = f2bf(h0[i]);
        hA1[i] = f2bf(h0[BATCH * HDIM + i]);
    }
}

// ---------------- bf16 MFMA GEMM: C[M,N] = A[M,K] * B[N,K]^T + bias[N] ----------------
#define BM 128
#define BN 128
#define BK 64

static __device__ __forceinline__ void g2l16(const unsigned short* g, void* lds) {
    __builtin_amdgcn_global_load_lds(
        (const __attribute__((address_space(1))) unsigned int*)g,
        (__attribute__((address_space(3))) unsigned int*)lds, 16, 0, 0);
}

__global__ __launch_bounds__(256)
void k_gemm_bt(const unsigned short* __restrict__ A,   // [M,K] bf16 bits
               const unsigned short* __restrict__ B,   // [N,K] bf16 bits
               const float* __restrict__ bias,         // [N]
               unsigned short* __restrict__ C,         // [M,N] bf16
               int M, int N, int K)
{
    __shared__ unsigned short As[BM * BK];  // XOR-swizzled rows of 128B
    __shared__ unsigned short Bs[BN * BK];
    const int tid = threadIdx.x;
    const int lane = tid & 63, wv = tid >> 6;
    const int nbn = N / BN;
    const int bm0 = (blockIdx.x / nbn) * BM;
    const int bn0 = (blockIdx.x % nbn) * BN;
    const int wr = wv >> 1, wc = wv & 1;   // 2x2 wave grid, each wave 64x64

    f32x4 acc[4][4];
#pragma unroll
    for (int i = 0; i < 4; i++)
#pragma unroll
        for (int j = 0; j < 4; j++) acc[i][j] = (f32x4){0.f, 0.f, 0.f, 0.f};

    const int srow = tid >> 3;          // staging row (per issue of 32 rows)
    const int scb  = (tid & 7) * 16;    // staging byte-col within 128B row

    for (int kt = 0; kt < K; kt += BK) {
        __syncthreads();
#pragma unroll
        for (int is = 0; is < 4; is++) {
            int row = is * 32 + srow;
            int kb = scb ^ ((row & 7) << 4);          // pre-swizzled global source
            g2l16(A + (size_t)(bm0 + row) * K + kt + (kb >> 1),
                  (char*)As + is * 4096 + wv * 1024);
        }
#pragma unroll
        for (int is = 0; is < 4; is++) {
            int row = is * 32 + srow;
            int kb = scb ^ ((row & 7) << 4);
            g2l16(B + (size_t)(bn0 + row) * K + kt + (kb >> 1),
                  (char*)Bs + is * 4096 + wv * 1024);
        }
        asm volatile("s_waitcnt vmcnt(0)" ::: "memory");
        __syncthreads();

#pragma unroll
        for (int ks = 0; ks < 2; ks++) {
            short8 a[4], b[4];
            const int kb = ks * 64 + ((lane >> 4) << 4);
#pragma unroll
            for (int mt = 0; mt < 4; mt++) {
                int r = wr * 64 + mt * 16 + (lane & 15);
                a[mt] = *reinterpret_cast<const short8*>(
                    (const char*)As + r * 128 + (kb ^ ((r & 7) << 4)));
            }
#pragma unroll
            for (int nt = 0; nt < 4; nt++) {
                int n = wc * 64 + nt * 16 + (lane & 15);
                b[nt] = *reinterpret_cast<const short8*>(
                    (const char*)Bs + n * 128 + (kb ^ ((n & 7) << 4)));
            }
#pragma unroll
            for (int mt = 0; mt < 4; mt++)
#pragma unroll
                for (int nt = 0; nt < 4; nt++)
                    acc[mt][nt] = __builtin_amdgcn_mfma_f32_16x16x32_bf16(
                        a[mt], b[nt], acc[mt][nt], 0, 0, 0);
        }
    }

    // epilogue: + bias, store bf16
#pragma unroll
    for (int nt = 0; nt < 4; nt++) {
        int cg = bn0 + wc * 64 + nt * 16 + (lane & 15);
        float bv = bias[cg];
#pragma unroll
        for (int mt = 0; mt < 4; mt++) {
#pragma unroll
            for (int e = 0; e < 4; e++) {
                int rg = bm0 + wr * 64 + mt * 16 + ((lane >> 4) << 2) + e;
                C[(size_t)rg * N + cg] = f2bf(acc[mt][nt][e] + bv);
            }
        }
    }
}

// ---------------- device-scope grid barrier (128 co-resident WGs) ----------------
__device__ __forceinline__ void grid_barrier(unsigned* bar) {
    __syncthreads();
    if (threadIdx.x == 0) {
        __threadfence();   // release our h writes (L2 writeback)
        unsigned gen = __hip_atomic_load(bar + 1, __ATOMIC_RELAXED, __HIP_MEMORY_SCOPE_AGENT);
        unsigned n = __hip_atomic_fetch_add(bar, 1u, __ATOMIC_ACQ_REL, __HIP_MEMORY_SCOPE_AGENT);
        if (n == gridDim.x - 1) {
            __hip_atomic_store(bar, 0u, __ATOMIC_RELAXED, __HIP_MEMORY_SCOPE_AGENT);
            __hip_atomic_store(bar + 1, gen + 1u, __ATOMIC_RELEASE, __HIP_MEMORY_SCOPE_AGENT);
        } else {
            while (__hip_atomic_load(bar + 1, __ATOMIC_RELAXED, __HIP_MEMORY_SCOPE_AGENT) == gen)
                __builtin_amdgcn_s_sleep(1);
        }
    }
    __syncthreads();
    __threadfence();       // acquire: invalidate L1/L2 before reading remote h
}

// ---------------- persistent LSTM scan (one layer) ----------------
// 128 WGs x 256 thr. WG g owns h-cols [8g,8g+8) -> 32 gate rows (i,f,g,o x 8).
// Weights persist in registers; waves split K (256 each); partials reduced in LDS.
__global__ __launch_bounds__(256)
void k_scan(const unsigned short* __restrict__ whh,   // [4096][1024] bf16
            const unsigned short* __restrict__ xw,    // [B*T][4096] bf16 (x-projections + biases)
            const float* __restrict__ c0,             // [64][1024] fp32 (this layer's slice)
            unsigned short* __restrict__ hA,          // [64][1024] bf16, holds h(t=-1) on entry
            unsigned short* __restrict__ hB,
            unsigned short* __restrict__ outseq,      // [B*T][1024] bf16 or nullptr
            float* __restrict__ hn, float* __restrict__ cn,  // [64][1024] fp32 outputs
            unsigned* __restrict__ bar)
{
    const int tid = threadIdx.x;
    const int lane = tid & 63, kw = tid >> 6;     // wave index = K-slice
    const int g = blockIdx.x;
    const int colbase = g * NHC;

    __shared__ float plds[4][64][34];             // [wave][row][gate-col(32)+pad]

    // --- persistent B-fragments: 32 gate rows x K=1024, this wave's K-slice ---
    short8 bfr[2][8];
    {
        const int c = lane & 15;
#pragma unroll
        for (int nt = 0; nt < 2; nt++) {
            int n = nt * 16 + c;                           // 0..31: [i(8) f(8) g(8) o(8)]
            int grow = (n >> 3) * HDIM + colbase + (n & 7); // global gate row
#pragma unroll
            for (int s = 0; s < 8; s++) {
                int k = kw * 256 + s * 32 + ((lane >> 4) << 3);
                bfr[nt][s] = *reinterpret_cast<const short8*>(whh + (size_t)grow * HDIM + k);
            }
        }
    }
    // --- c state: 2 values per thread, fp32, in registers ---
    float creg[2];
#pragma unroll
    for (int rep = 0; rep < 2; rep++) {
        int v = tid + rep * 256;
        int r = v >> 3, u = v & 7;
        creg[rep] = c0[r * HDIM + colbase + u];
    }

    const unsigned short* hr = hA;
    unsigned short* hw = hB;

    for (int t = 0; t < TSTEPS; t++) {
        // --- partial GEMM over this wave's K-slice ---
        f32x4 acc[4][2];
#pragma unroll
        for (int m = 0; m < 4; m++)
#pragma unroll
            for (int nt = 0; nt < 2; nt++) acc[m][nt] = (f32x4){0.f, 0.f, 0.f, 0.f};

        const int arow = lane & 15;
        const int koff = kw * 256 + ((lane >> 4) << 3);
#pragma unroll
        for (int s = 0; s < 8; s++) {
            short8 a[4];
#pragma unroll
            for (int m = 0; m < 4; m++) {
                int r = m * 16 + arow;
                a[m] = *reinterpret_cast<const short8*>(hr + (size_t)r * HDIM + koff + s * 32);
            }
#pragma unroll
            for (int m = 0; m < 4; m++)
#pragma unroll
                for (int nt = 0; nt < 2; nt++)
                    acc[m][nt] = __builtin_amdgcn_mfma_f32_16x16x32_bf16(
                        a[m], bfr[nt][s], acc[m][nt], 0, 0, 0);
        }
        // --- write partials to LDS ---
#pragma unroll
        for (int m = 0; m < 4; m++)
#pragma unroll
            for (int nt = 0; nt < 2; nt++) {
                int col = nt * 16 + (lane & 15);
                int rbase = m * 16 + ((lane >> 4) << 2);
#pragma unroll
                for (int e = 0; e < 4; e++)
                    plds[kw][rbase + e][col] = acc[m][nt][e];
            }
        __syncthreads();

        // --- reduce partials + pointwise LSTM cell (512 values, 2/thread) ---
#pragma unroll
        for (int rep = 0; rep < 2; rep++) {
            int v = tid + rep * 256;
            int r = v >> 3, u = v & 7;
            float s0 = 0.f, s1 = 0.f, s2 = 0.f, s3 = 0.f;
#pragma unroll
            for (int w = 0; w < 4; w++) {
                s0 += plds[w][r][u];
                s1 += plds[w][r][8 + u];
                s2 += plds[w][r][16 + u];
                s3 += plds[w][r][24 + u];
            }
            const unsigned short* xr = xw + (size_t)(r * TSTEPS + t) * G4 + colbase + u;
            s0 += bf2f(xr[0]);
            s1 += bf2f(xr[HDIM]);
            s2 += bf2f(xr[2 * HDIM]);
            s3 += bf2f(xr[3 * HDIM]);
            float ii = 1.f / (1.f + __expf(-s0));
            float ff = 1.f / (1.f + __expf(-s1));
            float gg = tanhf(s2);
            float oo = 1.f / (1.f + __expf(-s3));
            float c = ff * creg[rep] + ii * gg;
            creg[rep] = c;
            float h = oo * tanhf(c);
            int hi = r * HDIM + colbase + u;
            hw[hi] = f2bf(h);
            if (outseq) outseq[(size_t)(r * TSTEPS + t) * HDIM + colbase + u] = f2bf(h);
            if (t == TSTEPS - 1) { hn[hi] = h; cn[hi] = c; }
        }

        grid_barrier(bar);
        unsigned short* tmp = (unsigned short*)hr; hr = hw; hw = tmp;
    }
}

// ---------------- decode + log_softmax ----------------
__global__ __launch_bounds__(256)
void k_decode(const float* __restrict__ h1,    // [64][1024] fp32 (hn layer 1)
              const float* __restrict__ wdec,  // [512][1024]
              const float* __restrict__ bdec,  // [512]
              float* __restrict__ out)         // [64][512]
{
    __shared__ float hs[HDIM];
    __shared__ float ls[NINPUT];
    __shared__ float red[256];
    const int r = blockIdx.x, tid = threadIdx.x;
    reinterpret_cast<float4*>(hs)[tid] = reinterpret_cast<const float4*>(h1 + (size_t)r * HDIM)[tid];
    __syncthreads();
#pragma unroll
    for (int rep = 0; rep < 2; rep++) {
        int n = tid + rep * 256;
        float s = bdec[n];
        const float4* w4 = reinterpret_cast<const float4*>(wdec + (size_t)n * HDIM);
        for (int k = 0; k < HDIM / 4; k++) {
            float4 w = w4[k];
            float4 h4 = reinterpret_cast<const float4*>(hs)[k];
            s += w.x * h4.x + w.y * h4.y + w.z * h4.z + w.w * h4.w;
        }
        ls[n] = s;
    }
    __syncthreads();
    red[tid] = fmaxf(ls[tid], ls[tid + 256]);
    __syncthreads();
    for (int s2 = 128; s2 > 0; s2 >>= 1) {
        if (tid < s2) red[tid] = fmaxf(red[tid], red[tid + s2]);
        __syncthreads();
    }
    float M = red[0];
    __syncthreads();
    red[tid] = __expf(ls[tid] - M) + __expf(ls[tid + 256] - M);
    __syncthreads();
    for (int s2 = 128; s2 > 0; s2 >>= 1) {
        if (tid < s2) red[tid] += red[tid + s2];
        __syncthreads();
    }
    float lse = M + __logf(red[0]);
    out[(size_t)r * NINPUT + tid] = ls[tid] - lse;
    out[(size_t)r * NINPUT + tid + 256] = ls[tid + 256] - lse;
}

// ---------------- host launcher ----------------
extern "C" void kernel_launch(void* const* d_in, const int* in_sizes, int n_in,
                              void* d_out, int out_size, void* d_ws, size_t ws_size,
                              hipStream_t stream)
{
    const float* x    = (const float*)d_in[0];
    const float* h0   = (const float*)d_in[1];
    const float* c0   = (const float*)d_in[2];
    const float* wih0 = (const float*)d_in[3];
    const float* whh0 = (const float*)d_in[4];
    const float* bih0 = (const float*)d_in[5];
    const float* bhh0 = (const float*)d_in[6];
    const float* wih1 = (const float*)d_in[7];
    const float* whh1 = (const float*)d_in[8];
    const float* bih1 = (const float*)d_in[9];
    const float* bhh1 = (const float*)d_in[10];
    const float* wdec = (const float*)d_in[11];
    const float* bdec = (const float*)d_in[12];
    float* out = (float*)d_out;

    char* ws = (char*)d_ws;
    size_t off = 0;
    auto alloc = [&](size_t bytes) -> void* {
        void* p = ws + off;
        off += (bytes + 255) & ~(size_t)255;
        return p;
    };
    unsigned short* xw   = (unsigned short*)alloc((size_t)BATCH * TSTEPS * G4 * 2);
    unsigned short* out0 = (unsigned short*)alloc((size_t)BATCH * TSTEPS * HDIM * 2);
    unsigned short* xb   = (unsigned short*)alloc((size_t)BATCH * TSTEPS * NINPUT * 2);
    unsigned short* w0ib = (unsigned short*)alloc((size_t)G4 * NINPUT * 2);
    unsigned short* w0hb = (unsigned short*)alloc((size_t)G4 * HDIM * 2);
    unsigned short* w1ib = (unsigned short*)alloc((size_t)G4 * HDIM * 2);
    unsigned short* w1hb = (unsigned short*)alloc((size_t)G4 * HDIM * 2);
    float* bb0 = (float*)alloc(G4 * 4);
    float* bb1 = (float*)alloc(G4 * 4);
    unsigned short* hA0 = (unsigned short*)alloc(BATCH * HDIM * 2);
    unsigned short* hB0 = (unsigned short*)alloc(BATCH * HDIM * 2);
    unsigned short* hA1 = (unsigned short*)alloc(BATCH * HDIM * 2);
    unsigned short* hB1 = (unsigned short*)alloc(BATCH * HDIM * 2);
    unsigned* bar = (unsigned*)alloc(256);

    hipMemsetAsync(bar, 0, 8, stream);

    k_f2b<<<1024, 256, 0, stream>>>(x, xb, (long)BATCH * TSTEPS * NINPUT);
    k_f2b<<<512, 256, 0, stream>>>(wih0, w0ib, (long)G4 * NINPUT);
    k_f2b<<<1024, 256, 0, stream>>>(whh0, w0hb, (long)G4 * HDIM);
    k_f2b<<<1024, 256, 0, stream>>>(wih1, w1ib, (long)G4 * HDIM);
    k_f2b<<<1024, 256, 0, stream>>>(whh1, w1hb, (long)G4 * HDIM);
    k_prep_small<<<512, 256, 0, stream>>>(bih0, bhh0, bih1, bhh1, bb0, bb1, h0, hA0, hA1);

    const int M = BATCH * TSTEPS;
    // layer 0 input projection: xw = xb @ wih0^T + (bih0+bhh0)
    k_gemm_bt<<<(M / BM) * (G4 / BN), 256, 0, stream>>>(xb, w0ib, bb0, xw, M, G4, NINPUT);
    // layer 0 scan
    k_scan<<<NWG, 256, 0, stream>>>(w0hb, xw, c0, hA0, hB0, out0,
                                    out + 32768,
                                    out + 32768 + 2 * BATCH * HDIM, bar);
    // layer 1 input projection: xw = out0 @ wih1^T + (bih1+bhh1)
    k_gemm_bt<<<(M / BM) * (G4 / BN), 256, 0, stream>>>(out0, w1ib, bb1, xw, M, G4, HDIM);
    // layer 1 scan
    k_scan<<<NWG, 256, 0, stream>>>(w1hb, xw, c0 + BATCH * HDIM, hA1, hB1, nullptr,
                                    out + 32768 + BATCH * HDIM,
                                    out + 32768 + 2 * BATCH * HDIM + BATCH * HDIM, bar);
    // decode from fp32 final h of layer 1 (already in d_out)
    k_decode<<<BATCH, 256, 0, stream>>>(out + 32768 + BATCH * HDIM, wdec, bdec, out);
}

// Round 2
// 4766.462 us; speedup vs baseline: 2.4453x; 2.4453x over previous
//
#include <hip/hip_runtime.h>

#define BATCH   64
#define TSTEPS  256
#define NINPUT  512
#define HDIM    1024
#define G4      4096   // 4*HDIM
#define NWG     128    // scan workgroups
#define NHC     8      // h-columns owned per scan WG

typedef __attribute__((ext_vector_type(8))) short short8;
typedef __attribute__((ext_vector_type(4))) float f32x4;
typedef __attribute__((ext_vector_type(4))) unsigned int u32x4;

static __device__ __forceinline__ unsigned short f2bf(float x) {
    unsigned u = __float_as_uint(x);
    unsigned r = 0x7fffu + ((u >> 16) & 1u);
    return (unsigned short)((u + r) >> 16);
}
static __device__ __forceinline__ float bf2f(unsigned short b) {
    return __uint_as_float(((unsigned)b) << 16);
}

// ---------------- float -> bf16 conversion (vectorized, grid-stride) ----------------
__global__ void k_f2b(const float* __restrict__ in, unsigned short* __restrict__ out, long n) {
    long i = (long)blockIdx.x * blockDim.x + threadIdx.x;
    long stride = (long)gridDim.x * blockDim.x;
    for (long j = i * 4; j < n; j += stride * 4) {
        float4 v = *reinterpret_cast<const float4*>(in + j);
        ushort4 o;
        o.x = f2bf(v.x); o.y = f2bf(v.y); o.z = f2bf(v.z); o.w = f2bf(v.w);
        *reinterpret_cast<ushort4*>(out + j) = o;
    }
}

// ---------------- bias combine + h0 init ----------------
__global__ void k_prep_small(const float* __restrict__ bih0, const float* __restrict__ bhh0,
                             const float* __restrict__ bih1, const float* __restrict__ bhh1,
                             float* __restrict__ bb0, float* __restrict__ bb1,
                             const float* __restrict__ h0,
                             unsigned short* __restrict__ hA0, unsigned short* __restrict__ hA1) {
    int i = blockIdx.x * blockDim.x + threadIdx.x;
    if (i < G4) { bb0[i] = bih0[i] + bhh0[i]; bb1[i] = bih1[i] + bhh1[i]; }
    if (i < BATCH * HDIM) {
        hA0[i] = f2bf(h0[i]);
        hA1[i] = f2bf(h0[BATCH * HDIM + i]);
    }
}

// ---------------- bf16 MFMA GEMM: C[M,N] = A[M,K] * B[N,K]^T + bias[N] ----------------
#define BM 128
#define BN 128
#define BK 64

static __device__ __forceinline__ void g2l16(const unsigned short* g, void* lds) {
    __builtin_amdgcn_global_load_lds(
        (const __attribute__((address_space(1))) unsigned int*)g,
        (__attribute__((address_space(3))) unsigned int*)lds, 16, 0, 0);
}

__global__ __launch_bounds__(256)
void k_gemm_bt(const unsigned short* __restrict__ A,   // [M,K] bf16 bits
               const unsigned short* __restrict__ B,   // [N,K] bf16 bits
               const float* __restrict__ bias,         // [N]
               unsigned short* __restrict__ C,         // [M,N] bf16
               int M, int N, int K)
{
    __shared__ unsigned short As[BM * BK];  // XOR-swizzled rows of 128B
    __shared__ unsigned short Bs[BN * BK];
    const int tid = threadIdx.x;
    const int lane = tid & 63, wv = tid >> 6;
    const int nbn = N / BN;
    const int bm0 = (blockIdx.x / nbn) * BM;
    const int bn0 = (blockIdx.x % nbn) * BN;
    const int wr = wv >> 1, wc = wv & 1;   // 2x2 wave grid, each wave 64x64

    f32x4 acc[4][4];
#pragma unroll
    for (int i = 0; i < 4; i++)
#pragma unroll
        for (int j = 0; j < 4; j++) acc[i][j] = (f32x4){0.f, 0.f, 0.f, 0.f};

    const int srow = tid >> 3;          // staging row (per issue of 32 rows)
    const int scb  = (tid & 7) * 16;    // staging byte-col within 128B row

    for (int kt = 0; kt < K; kt += BK) {
        __syncthreads();
#pragma unroll
        for (int is = 0; is < 4; is++) {
            int row = is * 32 + srow;
            int kb = scb ^ ((row & 7) << 4);          // pre-swizzled global source
            g2l16(A + (size_t)(bm0 + row) * K + kt + (kb >> 1),
                  (char*)As + is * 4096 + wv * 1024);
        }
#pragma unroll
        for (int is = 0; is < 4; is++) {
            int row = is * 32 + srow;
            int kb = scb ^ ((row & 7) << 4);
            g2l16(B + (size_t)(bn0 + row) * K + kt + (kb >> 1),
                  (char*)Bs + is * 4096 + wv * 1024);
        }
        asm volatile("s_waitcnt vmcnt(0)" ::: "memory");
        __syncthreads();

#pragma unroll
        for (int ks = 0; ks < 2; ks++) {
            short8 a[4], b[4];
            const int kb = ks * 64 + ((lane >> 4) << 4);
#pragma unroll
            for (int mt = 0; mt < 4; mt++) {
                int r = wr * 64 + mt * 16 + (lane & 15);
                a[mt] = *reinterpret_cast<const short8*>(
                    (const char*)As + r * 128 + (kb ^ ((r & 7) << 4)));
            }
#pragma unroll
            for (int nt = 0; nt < 4; nt++) {
                int n = wc * 64 + nt * 16 + (lane & 15);
                b[nt] = *reinterpret_cast<const short8*>(
                    (const char*)Bs + n * 128 + (kb ^ ((n & 7) << 4)));
            }
#pragma unroll
            for (int mt = 0; mt < 4; mt++)
#pragma unroll
                for (int nt = 0; nt < 4; nt++)
                    acc[mt][nt] = __builtin_amdgcn_mfma_f32_16x16x32_bf16(
                        a[mt], b[nt], acc[mt][nt], 0, 0, 0);
        }
    }

    // epilogue: + bias, store bf16
#pragma unroll
    for (int nt = 0; nt < 4; nt++) {
        int cg = bn0 + wc * 64 + nt * 16 + (lane & 15);
        float bv = bias[cg];
#pragma unroll
        for (int mt = 0; mt < 4; mt++) {
#pragma unroll
            for (int e = 0; e < 4; e++) {
                int rg = bm0 + wr * 64 + mt * 16 + ((lane >> 4) << 2) + e;
                C[(size_t)rg * N + cg] = f2bf(acc[mt][nt][e] + bv);
            }
        }
    }
}

// ---------------- persistent LSTM scan (one layer) ----------------
// 128 WGs x 256 thr. WG g owns h-cols [8g,8g+8) -> 32 gate rows (i,f,g,o x 8).
// Weights persist in registers; waves split K (256 each); partials reduced in LDS.
// Cross-WG h exchange: sc0/sc1 (LLC-coherent) loads/stores, NO fences.
// Grid sync: monotonic relaxed counter, vmcnt(0) drain before arrival.
__global__ __launch_bounds__(256, 1)
void k_scan(const unsigned short* __restrict__ whh,   // [4096][1024] bf16
            const unsigned short* __restrict__ xw,    // [B*T][4096] bf16 (x-proj + biases)
            const float* __restrict__ c0,             // [64][1024] fp32 (this layer's slice)
            const unsigned short* __restrict__ hA,    // [64][1024] bf16, h(t=-1) on entry
            unsigned short* __restrict__ hB,
            unsigned short* __restrict__ outseq,      // [B*T][1024] bf16 or nullptr
            float* __restrict__ hn, float* __restrict__ cn,  // [64][1024] fp32 outputs
            unsigned* __restrict__ cnt)               // monotonic barrier counter (starts 0)
{
    const int tid = threadIdx.x;
    const int lane = tid & 63, kw = tid >> 6;     // wave index = K-slice
    const int colbase = blockIdx.x * NHC;

    __shared__ float plds[4][64][36];             // [wave][row][gate-col(32)+pad]

    // --- persistent B-fragments: 32 gate rows x K=1024, this wave's K-slice ---
    short8 bfr[2][8];
    {
        const int c = lane & 15;
#pragma unroll
        for (int nt = 0; nt < 2; nt++) {
            int n = nt * 16 + c;                            // 0..31: [i(8) f(8) g(8) o(8)]
            int grow = (n >> 3) * HDIM + colbase + (n & 7); // global gate row
#pragma unroll
            for (int s = 0; s < 8; s++) {
                int k = kw * 256 + s * 32 + ((lane >> 4) << 3);
                bfr[nt][s] = *reinterpret_cast<const short8*>(whh + (size_t)grow * HDIM + k);
            }
        }
    }

    // --- c state: this thread owns values (r2, u0) and (r2, u0+1) ---
    const int r2 = tid >> 2;
    const int u0 = (tid & 3) * 2;
    float c_a = c0[r2 * HDIM + colbase + u0];
    float c_b = c0[r2 * HDIM + colbase + u0 + 1];

    const unsigned short* hr = hA;
    unsigned short* hw = hB;

    const int arow = lane & 15;
    const size_t koff = (size_t)kw * 256 + ((lane >> 4) << 3);

    for (int t = 0; t < TSTEPS; t++) {
        // ---- issue xw prefetch (4 loads, cached) then 32 coherent h loads ----
        unsigned x0, x1, x2, x3;
        {
            const unsigned short* xr = xw + (size_t)(r2 * TSTEPS + t) * G4 + colbase + u0;
            const unsigned short* xr2 = xr + 2 * HDIM;
            asm volatile("global_load_dword %0, %1, off"             : "=v"(x0) : "v"(xr));
            asm volatile("global_load_dword %0, %1, off offset:2048" : "=v"(x1) : "v"(xr));
            asm volatile("global_load_dword %0, %1, off"             : "=v"(x2) : "v"(xr2));
            asm volatile("global_load_dword %0, %1, off offset:2048" : "=v"(x3) : "v"(xr2));
        }
        u32x4 afr[8][4];
        const unsigned short* pa0 = hr + (size_t)arow * HDIM + koff;
        const unsigned short* pa1 = pa0 + 16 * HDIM;
        const unsigned short* pa2 = pa0 + 32 * HDIM;
        const unsigned short* pa3 = pa0 + 48 * HDIM;
#define ISSUE4(S, OFFS) \
        asm volatile("global_load_dwordx4 %0, %1, off offset:" OFFS " sc0 sc1" : "=v"(afr[S][0]) : "v"(pa0)); \
        asm volatile("global_load_dwordx4 %0, %1, off offset:" OFFS " sc0 sc1" : "=v"(afr[S][1]) : "v"(pa1)); \
        asm volatile("global_load_dwordx4 %0, %1, off offset:" OFFS " sc0 sc1" : "=v"(afr[S][2]) : "v"(pa2)); \
        asm volatile("global_load_dwordx4 %0, %1, off offset:" OFFS " sc0 sc1" : "=v"(afr[S][3]) : "v"(pa3));
        ISSUE4(0, "0")   ISSUE4(1, "64")  ISSUE4(2, "128") ISSUE4(3, "192")
        ISSUE4(4, "256") ISSUE4(5, "320") ISSUE4(6, "384") ISSUE4(7, "448")
#undef ISSUE4

        f32x4 acc[4][2];
#pragma unroll
        for (int m = 0; m < 4; m++) {
            acc[m][0] = (f32x4){0.f, 0.f, 0.f, 0.f};
            acc[m][1] = (f32x4){0.f, 0.f, 0.f, 0.f};
        }

        // ---- 8 MFMA phases, counted vmcnt (xw issued first keeps constants valid) ----
#define MFMA_PHASE(S, VMS) \
        asm volatile("s_waitcnt vmcnt(" VMS ")" ::: "memory"); \
        __builtin_amdgcn_sched_barrier(0); \
        { _Pragma("unroll") \
          for (int m = 0; m < 4; m++) { \
            short8 av = __builtin_bit_cast(short8, afr[S][m]); \
            acc[m][0] = __builtin_amdgcn_mfma_f32_16x16x32_bf16(av, bfr[0][S], acc[m][0], 0, 0, 0); \
            acc[m][1] = __builtin_amdgcn_mfma_f32_16x16x32_bf16(av, bfr[1][S], acc[m][1], 0, 0, 0); \
          } }
        MFMA_PHASE(0, "28") MFMA_PHASE(1, "24") MFMA_PHASE(2, "20") MFMA_PHASE(3, "16")
        MFMA_PHASE(4, "12") MFMA_PHASE(5, "8")  MFMA_PHASE(6, "4")  MFMA_PHASE(7, "0")
#undef MFMA_PHASE

        // ---- write partials to LDS ----
#pragma unroll
        for (int m = 0; m < 4; m++)
#pragma unroll
            for (int nt = 0; nt < 2; nt++) {
                int col = nt * 16 + (lane & 15);
                int rb = m * 16 + ((lane >> 4) << 2);
#pragma unroll
                for (int e = 0; e < 4; e++)
                    plds[kw][rb + e][col] = acc[m][nt][e];
            }
        __syncthreads();

        // ---- reduce partials + pointwise LSTM cell (2 adjacent values/thread) ----
        float s0a = 0.f, s0b = 0.f, s1a = 0.f, s1b = 0.f;
        float s2a = 0.f, s2b = 0.f, s3a = 0.f, s3b = 0.f;
#pragma unroll
        for (int w = 0; w < 4; w++) {
            s0a += plds[w][r2][u0];          s0b += plds[w][r2][u0 + 1];
            s1a += plds[w][r2][8 + u0];      s1b += plds[w][r2][8 + u0 + 1];
            s2a += plds[w][r2][16 + u0];     s2b += plds[w][r2][16 + u0 + 1];
            s3a += plds[w][r2][24 + u0];     s3b += plds[w][r2][24 + u0 + 1];
        }
        s0a += bf2f((unsigned short)x0); s0b += bf2f((unsigned short)(x0 >> 16));
        s1a += bf2f((unsigned short)x1); s1b += bf2f((unsigned short)(x1 >> 16));
        s2a += bf2f((unsigned short)x2); s2b += bf2f((unsigned short)(x2 >> 16));
        s3a += bf2f((unsigned short)x3); s3b += bf2f((unsigned short)(x3 >> 16));

        float ia = 1.f / (1.f + __expf(-s0a)), ib = 1.f / (1.f + __expf(-s0b));
        float fa = 1.f / (1.f + __expf(-s1a)), fb = 1.f / (1.f + __expf(-s1b));
        float ga = tanhf(s2a),                 gb = tanhf(s2b);
        float oa = 1.f / (1.f + __expf(-s3a)), ob = 1.f / (1.f + __expf(-s3b));
        c_a = fa * c_a + ia * ga;
        c_b = fb * c_b + ib * gb;
        float ha = oa * tanhf(c_a);
        float hb = ob * tanhf(c_b);

        unsigned hv = (unsigned)f2bf(ha) | ((unsigned)f2bf(hb) << 16);
        const int hi = r2 * HDIM + colbase + u0;
        asm volatile("global_store_dword %0, %1, off sc0 sc1"
                     :: "v"(hw + hi), "v"(hv) : "memory");
        if (outseq)
            *(unsigned*)(outseq + (size_t)(r2 * TSTEPS + t) * HDIM + colbase + u0) = hv;
        if (t == TSTEPS - 1) {
            hn[hi] = ha; hn[hi + 1] = hb;
            cn[hi] = c_a; cn[hi + 1] = c_b;
        }

        // ---- grid barrier: relaxed monotonic counter (skip after last step) ----
        if (t != TSTEPS - 1) {
            asm volatile("s_waitcnt vmcnt(0)" ::: "memory");  // h stores visible at LLC
            __syncthreads();
            if (tid == 0) {
                __hip_atomic_fetch_add(cnt, 1u, __ATOMIC_RELAXED, __HIP_MEMORY_SCOPE_AGENT);
                const unsigned target = (unsigned)(t + 1) * NWG;
                while ((int)(__hip_atomic_load(cnt, __ATOMIC_RELAXED, __HIP_MEMORY_SCOPE_AGENT)
                             - target) < 0)
                    __builtin_amdgcn_s_sleep(2);
            }
            __syncthreads();
        }
        const unsigned short* tmp = hr; hr = hw; hw = (unsigned short*)const_cast<unsigned short*>(tmp);
    }
}

// ---------------- decode + log_softmax ----------------
__global__ __launch_bounds__(256)
void k_decode(const float* __restrict__ h1,    // [64][1024] fp32 (hn layer 1)
              const float* __restrict__ wdec,  // [512][1024]
              const float* __restrict__ bdec,  // [512]
              float* __restrict__ out)         // [64][512]
{
    __shared__ float hs[HDIM];
    __shared__ float ls[NINPUT];
    __shared__ float red[256];
    const int r = blockIdx.x, tid = threadIdx.x;
    reinterpret_cast<float4*>(hs)[tid] = reinterpret_cast<const float4*>(h1 + (size_t)r * HDIM)[tid];
    __syncthreads();
#pragma unroll
    for (int rep = 0; rep < 2; rep++) {
        int n = tid + rep * 256;
        float s = bdec[n];
        const float4* w4 = reinterpret_cast<const float4*>(wdec + (size_t)n * HDIM);
        for (int k = 0; k < HDIM / 4; k++) {
            float4 w = w4[k];
            float4 h4 = reinterpret_cast<const float4*>(hs)[k];
            s += w.x * h4.x + w.y * h4.y + w.z * h4.z + w.w * h4.w;
        }
        ls[n] = s;
    }
    __syncthreads();
    red[tid] = fmaxf(ls[tid], ls[tid + 256]);
    __syncthreads();
    for (int s2 = 128; s2 > 0; s2 >>= 1) {
        if (tid < s2) red[tid] = fmaxf(red[tid], red[tid + s2]);
        __syncthreads();
    }
    float M = red[0];
    __syncthreads();
    red[tid] = __expf(ls[tid] - M) + __expf(ls[tid + 256] - M);
    __syncthreads();
    for (int s2 = 128; s2 > 0; s2 >>= 1) {
        if (tid < s2) red[tid] += red[tid + s2];
        __syncthreads();
    }
    float lse = M + __logf(red[0]);
    out[(size_t)r * NINPUT + tid] = ls[tid] - lse;
    out[(size_t)r * NINPUT + tid + 256] = ls[tid + 256] - lse;
}

// ---------------- host launcher ----------------
extern "C" void kernel_launch(void* const* d_in, const int* in_sizes, int n_in,
                              void* d_out, int out_size, void* d_ws, size_t ws_size,
                              hipStream_t stream)
{
    const float* x    = (const float*)d_in[0];
    const float* h0   = (const float*)d_in[1];
    const float* c0   = (const float*)d_in[2];
    const float* wih0 = (const float*)d_in[3];
    const float* whh0 = (const float*)d_in[4];
    const float* bih0 = (const float*)d_in[5];
    const float* bhh0 = (const float*)d_in[6];
    const float* wih1 = (const float*)d_in[7];
    const float* whh1 = (const float*)d_in[8];
    const float* bih1 = (const float*)d_in[9];
    const float* bhh1 = (const float*)d_in[10];
    const float* wdec = (const float*)d_in[11];
    const float* bdec = (const float*)d_in[12];
    float* out = (float*)d_out;

    char* ws = (char*)d_ws;
    size_t off = 0;
    auto alloc = [&](size_t bytes) -> void* {
        void* p = ws + off;
        off += (bytes + 255) & ~(size_t)255;
        return p;
    };
    unsigned short* xw   = (unsigned short*)alloc((size_t)BATCH * TSTEPS * G4 * 2);
    unsigned short* out0 = (unsigned short*)alloc((size_t)BATCH * TSTEPS * HDIM * 2);
    unsigned short* xb   = (unsigned short*)alloc((size_t)BATCH * TSTEPS * NINPUT * 2);
    unsigned short* w0ib = (unsigned short*)alloc((size_t)G4 * NINPUT * 2);
    unsigned short* w0hb = (unsigned short*)alloc((size_t)G4 * HDIM * 2);
    unsigned short* w1ib = (unsigned short*)alloc((size_t)G4 * HDIM * 2);
    unsigned short* w1hb = (unsigned short*)alloc((size_t)G4 * HDIM * 2);
    float* bb0 = (float*)alloc(G4 * 4);
    float* bb1 = (float*)alloc(G4 * 4);
    unsigned short* hA0 = (unsigned short*)alloc(BATCH * HDIM * 2);
    unsigned short* hB0 = (unsigned short*)alloc(BATCH * HDIM * 2);
    unsigned short* hA1 = (unsigned short*)alloc(BATCH * HDIM * 2);
    unsigned short* hB1 = (unsigned short*)alloc(BATCH * HDIM * 2);
    unsigned* bar = (unsigned*)alloc(512);

    hipMemsetAsync(bar, 0, 512, stream);

    k_f2b<<<1024, 256, 0, stream>>>(x, xb, (long)BATCH * TSTEPS * NINPUT);
    k_f2b<<<512, 256, 0, stream>>>(wih0, w0ib, (long)G4 * NINPUT);
    k_f2b<<<1024, 256, 0, stream>>>(whh0, w0hb, (long)G4 * HDIM);
    k_f2b<<<1024, 256, 0, stream>>>(wih1, w1ib, (long)G4 * HDIM);
    k_f2b<<<1024, 256, 0, stream>>>(whh1, w1hb, (long)G4 * HDIM);
    k_prep_small<<<512, 256, 0, stream>>>(bih0, bhh0, bih1, bhh1, bb0, bb1, h0, hA0, hA1);

    const int M = BATCH * TSTEPS;
    // layer 0 input projection: xw = xb @ wih0^T + (bih0+bhh0)
    k_gemm_bt<<<(M / BM) * (G4 / BN), 256, 0, stream>>>(xb, w0ib, bb0, xw, M, G4, NINPUT);
    // layer 0 scan
    k_scan<<<NWG, 256, 0, stream>>>(w0hb, xw, c0, hA0, hB0, out0,
                                    out + 32768,
                                    out + 32768 + 2 * BATCH * HDIM, bar);
    // layer 1 input projection: xw = out0 @ wih1^T + (bih1+bhh1)
    k_gemm_bt<<<(M / BM) * (G4 / BN), 256, 0, stream>>>(out0, w1ib, bb1, xw, M, G4, HDIM);
    // layer 1 scan
    k_scan<<<NWG, 256, 0, stream>>>(w1hb, xw, c0 + BATCH * HDIM, hA1, hB1, nullptr,
                                    out + 32768 + BATCH * HDIM,
                                    out + 32768 + 2 * BATCH * HDIM + BATCH * HDIM, bar + 64);
    // decode from fp32 final h of layer 1 (already in d_out)
    k_decode<<<BATCH, 256, 0, stream>>>(out + 32768 + BATCH * HDIM, wdec, bdec, out);
}

// Round 3
// 4175.915 us; speedup vs baseline: 2.7912x; 1.1414x over previous
//
#include <hip/hip_runtime.h>

#define BATCH   64
#define TSTEPS  256
#define NINPUT  512
#define HDIM    1024
#define G4      4096   // 4*HDIM
#define NWG     64     // scan workgroups
#define NHC     16     // h-columns owned per scan WG

typedef __attribute__((ext_vector_type(8))) short short8;
typedef __attribute__((ext_vector_type(4))) float f32x4;
typedef __attribute__((ext_vector_type(4))) unsigned int u32x4;
typedef __attribute__((ext_vector_type(2))) unsigned int u32x2;

static __device__ __forceinline__ unsigned short f2bf(float x) {
    unsigned u = __float_as_uint(x);
    unsigned r = 0x7fffu + ((u >> 16) & 1u);
    return (unsigned short)((u + r) >> 16);
}
static __device__ __forceinline__ float bf2f(unsigned short b) {
    return __uint_as_float(((unsigned)b) << 16);
}
static __device__ __forceinline__ float sigf(float x) {
    return 1.f / (1.f + __expf(-x));
}

// ---------------- float -> bf16 conversion (vectorized, grid-stride) ----------------
__global__ void k_f2b(const float* __restrict__ in, unsigned short* __restrict__ out, long n) {
    long i = (long)blockIdx.x * blockDim.x + threadIdx.x;
    long stride = (long)gridDim.x * blockDim.x;
    for (long j = i * 4; j < n; j += stride * 4) {
        float4 v = *reinterpret_cast<const float4*>(in + j);
        ushort4 o;
        o.x = f2bf(v.x); o.y = f2bf(v.y); o.z = f2bf(v.z); o.w = f2bf(v.w);
        *reinterpret_cast<ushort4*>(out + j) = o;
    }
}

// ---------------- bias combine + h0 init ----------------
__global__ void k_prep_small(const float* __restrict__ bih0, const float* __restrict__ bhh0,
                             const float* __restrict__ bih1, const float* __restrict__ bhh1,
                             float* __restrict__ bb0, float* __restrict__ bb1,
                             const float* __restrict__ h0,
                             unsigned short* __restrict__ hA0, unsigned short* __restrict__ hA1) {
    int i = blockIdx.x * blockDim.x + threadIdx.x;
    if (i < G4) { bb0[i] = bih0[i] + bhh0[i]; bb1[i] = bih1[i] + bhh1[i]; }
    if (i < BATCH * HDIM) {
        hA0[i] = f2bf(h0[i]);
        hA1[i] = f2bf(h0[BATCH * HDIM + i]);
    }
}

// ---------------- bf16 MFMA GEMM: C[M,N] = A[M,K] * B[N,K]^T + bias[N] ----------------
#define BM 128
#define BN 128
#define BK 64

static __device__ __forceinline__ void g2l16(const unsigned short* g, void* lds) {
    __builtin_amdgcn_global_load_lds(
        (const __attribute__((address_space(1))) unsigned int*)g,
        (__attribute__((address_space(3))) unsigned int*)lds, 16, 0, 0);
}

__global__ __launch_bounds__(256)
void k_gemm_bt(const unsigned short* __restrict__ A,   // [M,K] bf16 bits
               const unsigned short* __restrict__ B,   // [N,K] bf16 bits
               const float* __restrict__ bias,         // [N]
               unsigned short* __restrict__ C,         // [M,N] bf16
               int M, int N, int K)
{
    __shared__ unsigned short As[BM * BK];  // XOR-swizzled rows of 128B
    __shared__ unsigned short Bs[BN * BK];
    const int tid = threadIdx.x;
    const int lane = tid & 63, wv = tid >> 6;
    const int nbn = N / BN;
    const int bm0 = (blockIdx.x / nbn) * BM;
    const int bn0 = (blockIdx.x % nbn) * BN;
    const int wr = wv >> 1, wc = wv & 1;   // 2x2 wave grid, each wave 64x64

    f32x4 acc[4][4];
#pragma unroll
    for (int i = 0; i < 4; i++)
#pragma unroll
        for (int j = 0; j < 4; j++) acc[i][j] = (f32x4){0.f, 0.f, 0.f, 0.f};

    const int srow = tid >> 3;          // staging row (per issue of 32 rows)
    const int scb  = (tid & 7) * 16;    // staging byte-col within 128B row

    for (int kt = 0; kt < K; kt += BK) {
        __syncthreads();
#pragma unroll
        for (int is = 0; is < 4; is++) {
            int row = is * 32 + srow;
            int kb = scb ^ ((row & 7) << 4);          // pre-swizzled global source
            g2l16(A + (size_t)(bm0 + row) * K + kt + (kb >> 1),
                  (char*)As + is * 4096 + wv * 1024);
        }
#pragma unroll
        for (int is = 0; is < 4; is++) {
            int row = is * 32 + srow;
            int kb = scb ^ ((row & 7) << 4);
            g2l16(B + (size_t)(bn0 + row) * K + kt + (kb >> 1),
                  (char*)Bs + is * 4096 + wv * 1024);
        }
        asm volatile("s_waitcnt vmcnt(0)" ::: "memory");
        __syncthreads();

#pragma unroll
        for (int ks = 0; ks < 2; ks++) {
            short8 a[4], b[4];
            const int kb = ks * 64 + ((lane >> 4) << 4);
#pragma unroll
            for (int mt = 0; mt < 4; mt++) {
                int r = wr * 64 + mt * 16 + (lane & 15);
                a[mt] = *reinterpret_cast<const short8*>(
                    (const char*)As + r * 128 + (kb ^ ((r & 7) << 4)));
            }
#pragma unroll
            for (int nt = 0; nt < 4; nt++) {
                int n = wc * 64 + nt * 16 + (lane & 15);
                b[nt] = *reinterpret_cast<const short8*>(
                    (const char*)Bs + n * 128 + (kb ^ ((n & 7) << 4)));
            }
#pragma unroll
            for (int mt = 0; mt < 4; mt++)
#pragma unroll
                for (int nt = 0; nt < 4; nt++)
                    acc[mt][nt] = __builtin_amdgcn_mfma_f32_16x16x32_bf16(
                        a[mt], b[nt], acc[mt][nt], 0, 0, 0);
        }
    }

    // epilogue: + bias, store bf16
#pragma unroll
    for (int nt = 0; nt < 4; nt++) {
        int cg = bn0 + wc * 64 + nt * 16 + (lane & 15);
        float bv = bias[cg];
#pragma unroll
        for (int mt = 0; mt < 4; mt++) {
#pragma unroll
            for (int e = 0; e < 4; e++) {
                int rg = bm0 + wr * 64 + mt * 16 + ((lane >> 4) << 2) + e;
                C[(size_t)rg * N + cg] = f2bf(acc[mt][nt][e] + bv);
            }
        }
    }
}

// ---------------- persistent LSTM scan (one layer) ----------------
// 64 WGs x 256 thr. WG g owns h-cols [16g,16g+16) -> 64 gate rows (i,f,g,o x 16).
// Weights persist in registers; waves split K (256 each); partials reduced in LDS
// in two passes (gates i,f then g,o). Cross-WG h: sc0/sc1 LLC-coherent ops.
// Grid sync: per-WG store-slot barrier (no atomics), wave0 gathers 64 slots.
__global__ __launch_bounds__(256, 1)
void k_scan(const unsigned short* __restrict__ whh,   // [4096][1024] bf16
            const unsigned short* __restrict__ xw,    // [B*T][4096] bf16 (x-proj + biases)
            const float* __restrict__ c0,             // [64][1024] fp32 (this layer's slice)
            const unsigned short* __restrict__ hA,    // [64][1024] bf16, h(t=-1) on entry
            unsigned short* __restrict__ hB,
            unsigned short* __restrict__ outseq,      // [B*T][1024] bf16 or nullptr
            float* __restrict__ hn, float* __restrict__ cn,  // [64][1024] fp32 outputs
            unsigned* __restrict__ slots)             // 64 slots, 16-u32 (64B) stride, zeroed
{
    const int tid = threadIdx.x;
    const int lane = tid & 63, kw = tid >> 6;     // wave index = K-slice
    const int colbase = blockIdx.x * NHC;

    __shared__ float plds[4][64][34];             // [wave][batch-row][2 gates x 16 + pad]

    // --- persistent B-fragments: 4 gates x 16 cols, this wave's K-slice (256) ---
    short8 bfr[4][8];
    {
        const int c = lane & 15;
#pragma unroll
        for (int g = 0; g < 4; g++) {
            int grow = g * HDIM + colbase + c;       // gate g, owned col c
#pragma unroll
            for (int s = 0; s < 8; s++) {
                int k = kw * 256 + s * 32 + ((lane >> 4) << 3);
                bfr[g][s] = *reinterpret_cast<const short8*>(whh + (size_t)grow * HDIM + k);
            }
        }
    }

    // --- c state: thread owns batch row r2, cols u0..u0+3 ---
    const int r2 = tid >> 2;
    const int u0 = (tid & 3) * 4;
    f32x4 cst = *reinterpret_cast<const f32x4*>(c0 + (size_t)r2 * HDIM + colbase + u0);

    const unsigned short* hr = hA;
    unsigned short* hw = hB;
    const int arow = lane & 15;
    const size_t koff = (size_t)kw * 256 + ((lane >> 4) << 3);

    u32x2 xv[4];   // per-gate 4 bf16 of xw (prefetched across barrier)
#define XW_PREFETCH(T) { \
        const unsigned short* xp = xw + ((size_t)r2 * TSTEPS + (T)) * G4 + colbase + u0; \
        asm volatile("global_load_dwordx2 %0, %1, off"             : "=v"(xv[0]) : "v"(xp)); \
        asm volatile("global_load_dwordx2 %0, %1, off offset:2048" : "=v"(xv[1]) : "v"(xp)); \
        asm volatile("global_load_dwordx2 %0, %1, off"             : "=v"(xv[2]) : "v"(xp + 2048)); \
        asm volatile("global_load_dwordx2 %0, %1, off offset:2048" : "=v"(xv[3]) : "v"(xp + 2048)); }

    XW_PREFETCH(0)

    for (int t = 0; t < TSTEPS; t++) {
        // ---- 32 coherent h loads (A-fragments: 64 batch rows x K-slice 256) ----
        u32x4 afr[8][4];
        const unsigned short* pa0 = hr + (size_t)arow * HDIM + koff;
        const unsigned short* pa1 = pa0 + 16 * HDIM;
        const unsigned short* pa2 = pa0 + 32 * HDIM;
        const unsigned short* pa3 = pa0 + 48 * HDIM;
#define ISSUE4(S, OFFS) \
        asm volatile("global_load_dwordx4 %0, %1, off offset:" OFFS " sc0 sc1" : "=v"(afr[S][0]) : "v"(pa0)); \
        asm volatile("global_load_dwordx4 %0, %1, off offset:" OFFS " sc0 sc1" : "=v"(afr[S][1]) : "v"(pa1)); \
        asm volatile("global_load_dwordx4 %0, %1, off offset:" OFFS " sc0 sc1" : "=v"(afr[S][2]) : "v"(pa2)); \
        asm volatile("global_load_dwordx4 %0, %1, off offset:" OFFS " sc0 sc1" : "=v"(afr[S][3]) : "v"(pa3));
        ISSUE4(0, "0")   ISSUE4(1, "64")  ISSUE4(2, "128") ISSUE4(3, "192")
        ISSUE4(4, "256") ISSUE4(5, "320") ISSUE4(6, "384") ISSUE4(7, "448")
#undef ISSUE4

        f32x4 acc[4][4];
#pragma unroll
        for (int m = 0; m < 4; m++)
#pragma unroll
            for (int g = 0; g < 4; g++) acc[m][g] = (f32x4){0.f, 0.f, 0.f, 0.f};

        // ---- 8 MFMA phases, counted vmcnt ----
#define MFMA_PHASE(S, VMS) \
        asm volatile("s_waitcnt vmcnt(" VMS ")" ::: "memory"); \
        __builtin_amdgcn_sched_barrier(0); \
        { _Pragma("unroll") \
          for (int m = 0; m < 4; m++) { \
            short8 av = __builtin_bit_cast(short8, afr[S][m]); \
            _Pragma("unroll") \
            for (int g = 0; g < 4; g++) \
                acc[m][g] = __builtin_amdgcn_mfma_f32_16x16x32_bf16(av, bfr[g][S], acc[m][g], 0, 0, 0); \
          } }
        MFMA_PHASE(0, "28") MFMA_PHASE(1, "24") MFMA_PHASE(2, "20") MFMA_PHASE(3, "16")
        MFMA_PHASE(4, "12") MFMA_PHASE(5, "8")  MFMA_PHASE(6, "4")  MFMA_PHASE(7, "0")
#undef MFMA_PHASE

        // ---- pass A: partials for gates i,f -> LDS -> reduce ----
#pragma unroll
        for (int m = 0; m < 4; m++)
#pragma unroll
            for (int g = 0; g < 2; g++) {
                int col = g * 16 + (lane & 15);
                int rb = m * 16 + ((lane >> 4) << 2);
#pragma unroll
                for (int e = 0; e < 4; e++)
                    plds[kw][rb + e][col] = acc[m][g][e];
            }
        __syncthreads();
        f32x4 sI = (f32x4){0.f,0.f,0.f,0.f}, sF = sI;
#pragma unroll
        for (int w = 0; w < 4; w++) {
            sI += *reinterpret_cast<const f32x4*>(&plds[w][r2][u0]);
            sF += *reinterpret_cast<const f32x4*>(&plds[w][r2][16 + u0]);
        }
        __syncthreads();
        // ---- pass B: partials for gates g,o ----
#pragma unroll
        for (int m = 0; m < 4; m++)
#pragma unroll
            for (int g = 2; g < 4; g++) {
                int col = (g - 2) * 16 + (lane & 15);
                int rb = m * 16 + ((lane >> 4) << 2);
#pragma unroll
                for (int e = 0; e < 4; e++)
                    plds[kw][rb + e][col] = acc[m][g][e];
            }
        __syncthreads();
        f32x4 sG = (f32x4){0.f,0.f,0.f,0.f}, sO = sG;
#pragma unroll
        for (int w = 0; w < 4; w++) {
            sG += *reinterpret_cast<const f32x4*>(&plds[w][r2][u0]);
            sO += *reinterpret_cast<const f32x4*>(&plds[w][r2][16 + u0]);
        }

        // ---- add xw, pointwise LSTM cell (4 values/thread) ----
#define ADDX(S, G) { unsigned lo = xv[G][0], hi = xv[G][1]; \
        S[0] += bf2f((unsigned short)lo); S[1] += bf2f((unsigned short)(lo >> 16)); \
        S[2] += bf2f((unsigned short)hi); S[3] += bf2f((unsigned short)(hi >> 16)); }
        ADDX(sI, 0) ADDX(sF, 1) ADDX(sG, 2) ADDX(sO, 3)
#undef ADDX

        float hv[4];
#pragma unroll
        for (int j = 0; j < 4; j++) {
            float c = sigf(sF[j]) * cst[j] + sigf(sI[j]) * tanhf(sG[j]);
            cst[j] = c;
            hv[j] = sigf(sO[j]) * tanhf(c);
        }
        u32x2 hp;
        hp[0] = (unsigned)f2bf(hv[0]) | ((unsigned)f2bf(hv[1]) << 16);
        hp[1] = (unsigned)f2bf(hv[2]) | ((unsigned)f2bf(hv[3]) << 16);
        const size_t hi_ = (size_t)r2 * HDIM + colbase + u0;
        asm volatile("global_store_dwordx2 %0, %1, off sc0 sc1"
                     :: "v"(hw + hi_), "v"(hp) : "memory");
        if (outseq)
            *reinterpret_cast<u32x2*>(outseq + ((size_t)r2 * TSTEPS + t) * HDIM + colbase + u0) = hp;
        if (t == TSTEPS - 1) {
            *reinterpret_cast<f32x4*>(hn + hi_) = (f32x4){hv[0], hv[1], hv[2], hv[3]};
            *reinterpret_cast<f32x4*>(cn + hi_) = cst;
        }

        // ---- store-slot grid barrier (skip after last step) ----
        if (t != TSTEPS - 1) {
            XW_PREFETCH(t + 1)                                  // overlap with barrier
            asm volatile("s_waitcnt vmcnt(4)" ::: "memory");    // h (+outseq) drained; xw in flight
            __syncthreads();
            if (kw == 0) {
                const unsigned tgt = (unsigned)(t + 1);
                if (lane == 0)
                    asm volatile("global_store_dword %0, %1, off sc0 sc1"
                                 :: "v"(slots + (size_t)blockIdx.x * 16), "v"(tgt) : "memory");
                const unsigned* sp = slots + (size_t)lane * 16;
                unsigned v;
                do {
                    __builtin_amdgcn_s_sleep(1);
                    asm volatile("global_load_dword %0, %1, off sc0 sc1" : "=v"(v) : "v"(sp));
                    asm volatile("s_waitcnt vmcnt(0)" ::: "memory");
                } while (__any(v < tgt));
            }
            __syncthreads();
        }
        const unsigned short* tmp = hr; hr = hw; hw = (unsigned short*)tmp;
    }
#undef XW_PREFETCH
}

// ---------------- decode + log_softmax ----------------
__global__ __launch_bounds__(256)
void k_decode(const float* __restrict__ h1,    // [64][1024] fp32 (hn layer 1)
              const float* __restrict__ wdec,  // [512][1024]
              const float* __restrict__ bdec,  // [512]
              float* __restrict__ out)         // [64][512]
{
    __shared__ float hs[HDIM];
    __shared__ float ls[NINPUT];
    __shared__ float red[256];
    const int r = blockIdx.x, tid = threadIdx.x;
    reinterpret_cast<float4*>(hs)[tid] = reinterpret_cast<const float4*>(h1 + (size_t)r * HDIM)[tid];
    __syncthreads();
#pragma unroll
    for (int rep = 0; rep < 2; rep++) {
        int n = tid + rep * 256;
        float s = bdec[n];
        const float4* w4 = reinterpret_cast<const float4*>(wdec + (size_t)n * HDIM);
        for (int k = 0; k < HDIM / 4; k++) {
            float4 w = w4[k];
            float4 h4 = reinterpret_cast<const float4*>(hs)[k];
            s += w.x * h4.x + w.y * h4.y + w.z * h4.z + w.w * h4.w;
        }
        ls[n] = s;
    }
    __syncthreads();
    red[tid] = fmaxf(ls[tid], ls[tid + 256]);
    __syncthreads();
    for (int s2 = 128; s2 > 0; s2 >>= 1) {
        if (tid < s2) red[tid] = fmaxf(red[tid], red[tid + s2]);
        __syncthreads();
    }
    float M = red[0];
    __syncthreads();
    red[tid] = __expf(ls[tid] - M) + __expf(ls[tid + 256] - M);
    __syncthreads();
    for (int s2 = 128; s2 > 0; s2 >>= 1) {
        if (tid < s2) red[tid] += red[tid + s2];
        __syncthreads();
    }
    float lse = M + __logf(red[0]);
    out[(size_t)r * NINPUT + tid] = ls[tid] - lse;
    out[(size_t)r * NINPUT + tid + 256] = ls[tid + 256] - lse;
}

// ---------------- host launcher ----------------
extern "C" void kernel_launch(void* const* d_in, const int* in_sizes, int n_in,
                              void* d_out, int out_size, void* d_ws, size_t ws_size,
                              hipStream_t stream)
{
    const float* x    = (const float*)d_in[0];
    const float* h0   = (const float*)d_in[1];
    const float* c0   = (const float*)d_in[2];
    const float* wih0 = (const float*)d_in[3];
    const float* whh0 = (const float*)d_in[4];
    const float* bih0 = (const float*)d_in[5];
    const float* bhh0 = (const float*)d_in[6];
    const float* wih1 = (const float*)d_in[7];
    const float* whh1 = (const float*)d_in[8];
    const float* bih1 = (const float*)d_in[9];
    const float* bhh1 = (const float*)d_in[10];
    const float* wdec = (const float*)d_in[11];
    const float* bdec = (const float*)d_in[12];
    float* out = (float*)d_out;

    char* ws = (char*)d_ws;
    size_t off = 0;
    auto alloc = [&](size_t bytes) -> void* {
        void* p = ws + off;
        off += (bytes + 255) & ~(size_t)255;
        return p;
    };
    unsigned short* xw   = (unsigned short*)alloc((size_t)BATCH * TSTEPS * G4 * 2);
    unsigned short* out0 = (unsigned short*)alloc((size_t)BATCH * TSTEPS * HDIM * 2);
    unsigned short* xb   = (unsigned short*)alloc((size_t)BATCH * TSTEPS * NINPUT * 2);
    unsigned short* w0ib = (unsigned short*)alloc((size_t)G4 * NINPUT * 2);
    unsigned short* w0hb = (unsigned short*)alloc((size_t)G4 * HDIM * 2);
    unsigned short* w1ib = (unsigned short*)alloc((size_t)G4 * HDIM * 2);
    unsigned short* w1hb = (unsigned short*)alloc((size_t)G4 * HDIM * 2);
    float* bb0 = (float*)alloc(G4 * 4);
    float* bb1 = (float*)alloc(G4 * 4);
    unsigned short* hA0 = (unsigned short*)alloc(BATCH * HDIM * 2);
    unsigned short* hB0 = (unsigned short*)alloc(BATCH * HDIM * 2);
    unsigned short* hA1 = (unsigned short*)alloc(BATCH * HDIM * 2);
    unsigned short* hB1 = (unsigned short*)alloc(BATCH * HDIM * 2);
    unsigned* bar = (unsigned*)alloc(8192);

    hipMemsetAsync(bar, 0, 8192, stream);

    k_f2b<<<1024, 256, 0, stream>>>(x, xb, (long)BATCH * TSTEPS * NINPUT);
    k_f2b<<<512, 256, 0, stream>>>(wih0, w0ib, (long)G4 * NINPUT);
    k_f2b<<<1024, 256, 0, stream>>>(whh0, w0hb, (long)G4 * HDIM);
    k_f2b<<<1024, 256, 0, stream>>>(wih1, w1ib, (long)G4 * HDIM);
    k_f2b<<<1024, 256, 0, stream>>>(whh1, w1hb, (long)G4 * HDIM);
    k_prep_small<<<512, 256, 0, stream>>>(bih0, bhh0, bih1, bhh1, bb0, bb1, h0, hA0, hA1);

    const int M = BATCH * TSTEPS;
    // layer 0 input projection: xw = xb @ wih0^T + (bih0+bhh0)
    k_gemm_bt<<<(M / BM) * (G4 / BN), 256, 0, stream>>>(xb, w0ib, bb0, xw, M, G4, NINPUT);
    // layer 0 scan
    k_scan<<<NWG, 256, 0, stream>>>(w0hb, xw, c0, hA0, hB0, out0,
                                    out + 32768,
                                    out + 32768 + 2 * BATCH * HDIM, bar);
    // layer 1 input projection: xw = out0 @ wih1^T + (bih1+bhh1)
    k_gemm_bt<<<(M / BM) * (G4 / BN), 256, 0, stream>>>(out0, w1ib, bb1, xw, M, G4, HDIM);
    // layer 1 scan
    k_scan<<<NWG, 256, 0, stream>>>(w1hb, xw, c0 + BATCH * HDIM, hA1, hB1, nullptr,
                                    out + 32768 + BATCH * HDIM,
                                    out + 32768 + 2 * BATCH * HDIM + BATCH * HDIM, bar + 1024);
    // decode from fp32 final h of layer 1 (already in d_out)
    k_decode<<<BATCH, 256, 0, stream>>>(out + 32768 + BATCH * HDIM, wdec, bdec, out);
}